// Round 2
// baseline (803.284 us; speedup 1.0000x reference)
//
#include <hip/hip_runtime.h>
#include <hip/hip_bf16.h>

#define NN 50000
#define NE 800000
#define DD 128
#define HH 8
#define CC 16
#define DFF 512
#define ED 16

// ---------------- utility ----------------
__global__ void zero_int_k(int* __restrict__ a, int n) {
    int i = blockIdx.x * 256 + threadIdx.x;
    if (i < n) a[i] = 0;
}

// ---------------- CSR build ----------------
__global__ void count_k(const int* __restrict__ dst, int* __restrict__ cnt) {
    int e = blockIdx.x * 256 + threadIdx.x;
    if (e < NE) atomicAdd(&cnt[dst[e]], 1);
}

// single block, 1024 threads: exclusive scan of cnt[NN] -> row_start[NN+1]; cnt becomes cursor copy
__global__ void scan_k(int* __restrict__ cnt, int* __restrict__ row_start) {
    __shared__ int part[1024];
    int t = threadIdx.x;
    const int CH = (NN + 1023) / 1024;  // 49
    int lo = t * CH;
    int hi = lo + CH; if (hi > NN) hi = NN; if (lo > NN) lo = NN;
    int s = 0;
    for (int i = lo; i < hi; i++) s += cnt[i];
    part[t] = s;
    __syncthreads();
    for (int off = 1; off < 1024; off <<= 1) {
        int v = (t >= off) ? part[t - off] : 0;
        __syncthreads();
        part[t] += v;
        __syncthreads();
    }
    int run = part[t] - s;  // exclusive prefix
    for (int i = lo; i < hi; i++) {
        int c = cnt[i];
        row_start[i] = run;
        cnt[i] = run;   // cursor copy
        run += c;
    }
    if (t == 1023) row_start[NN] = part[1023];
}

__global__ void scatter_k(const int* __restrict__ ei, int* __restrict__ cursor,
                          int* __restrict__ e_src, int* __restrict__ perm) {
    int e = blockIdx.x * 256 + threadIdx.x;
    if (e >= NE) return;
    int s = ei[e];
    int d = ei[NE + e];
    int pos = atomicAdd(&cursor[d], 1);
    e_src[pos] = s;
    perm[e] = pos;
}

// ---------------- edge scores s_e = (ew @ We reshaped . a_e).sum ----------------
// folded: s_e[e,h] = sum_k ew[e,k] * Ae[k,h], Ae[k,h] = sum_c We[k, h*16+c]*ae[h,c]
__global__ void se_k(const float* __restrict__ ew, const float* __restrict__ We,
                     const float* __restrict__ ae, const int* __restrict__ perm,
                     float* __restrict__ s_e) {
    __shared__ float Ae[ED * HH];  // [k][h] -> Ae[k*8+h]
    int t = threadIdx.x;
    if (t < ED * HH) {
        int k = t >> 3, h = t & 7;
        float s = 0.f;
#pragma unroll
        for (int c = 0; c < CC; c++) s += We[k * DD + h * CC + c] * ae[h * CC + c];
        Ae[t] = s;
    }
    __syncthreads();
    int e = blockIdx.x * 256 + t;
    if (e >= NE) return;
    const float* ep = &ew[(size_t)e * ED];
    float4 v0 = *(const float4*)(ep);
    float4 v1 = *(const float4*)(ep + 4);
    float4 v2 = *(const float4*)(ep + 8);
    float4 v3 = *(const float4*)(ep + 12);
    float ev[16] = {v0.x, v0.y, v0.z, v0.w, v1.x, v1.y, v1.z, v1.w,
                    v2.x, v2.y, v2.z, v2.w, v3.x, v3.y, v3.z, v3.w};
    float o[8] = {0, 0, 0, 0, 0, 0, 0, 0};
#pragma unroll
    for (int k = 0; k < 16; k++) {
        float v = ev[k];
#pragma unroll
        for (int h = 0; h < 8; h++) o[h] += v * Ae[k * 8 + h];
    }
    int pp = perm[e];
    *(float4*)&s_e[(size_t)pp * 8]     = make_float4(o[0], o[1], o[2], o[3]);
    *(float4*)&s_e[(size_t)pp * 8 + 4] = make_float4(o[4], o[5], o[6], o[7]);
}

// ---------------- node GEMM: Y[n,d] = sum_k X[n,k] W[k,d] ----------------
// 64 nodes x 128 cols / block; each thread: 2 d-cols x 16 nodes (32 FMA / k-step)
__global__ __launch_bounds__(256) void gemm_k(const float* __restrict__ X,
                                              const float* __restrict__ W,
                                              float* __restrict__ Y) {
    __shared__ float xT[128][68];  // [k][node], padded
    int t = threadIdx.x;
    int nb0 = blockIdx.x * 64;
    for (int i = t; i < 64 * 128; i += 256) {
        int k = i & 127, nb = i >> 7;
        int n = nb0 + nb;
        xT[k][nb] = (n < NN) ? X[(size_t)n * DD + k] : 0.f;
    }
    __syncthreads();
    int d0 = (t & 63) * 2;
    int ngrp = t >> 6;  // wave-uniform -> LDS broadcast reads
    float2 acc[16];
#pragma unroll
    for (int i = 0; i < 16; i++) acc[i] = make_float2(0.f, 0.f);
    for (int k = 0; k < 128; k++) {
        float2 w = *(const float2*)&W[(size_t)k * DD + d0];
        const float* xp = &xT[k][ngrp * 16];
        float4 a0 = *(const float4*)(xp);
        float4 a1 = *(const float4*)(xp + 4);
        float4 a2 = *(const float4*)(xp + 8);
        float4 a3 = *(const float4*)(xp + 12);
        float xs[16] = {a0.x, a0.y, a0.z, a0.w, a1.x, a1.y, a1.z, a1.w,
                        a2.x, a2.y, a2.z, a2.w, a3.x, a3.y, a3.z, a3.w};
#pragma unroll
        for (int i = 0; i < 16; i++) {
            acc[i].x = fmaf(w.x, xs[i], acc[i].x);
            acc[i].y = fmaf(w.y, xs[i], acc[i].y);
        }
    }
#pragma unroll
    for (int i = 0; i < 16; i++) {
        int n = nb0 + ngrp * 16 + i;
        if (n < NN) *(float2*)&Y[(size_t)n * DD + d0] = acc[i];
    }
}

// ---------------- s_src/s_dst from xh (exact reference reduction order) ----------------
__global__ void ssd_k(const float* __restrict__ xh, const float* __restrict__ a_src,
                      const float* __restrict__ a_dst, float* __restrict__ s_src,
                      float* __restrict__ s_dst) {
    __shared__ float as[128], ad[128];
    if (threadIdx.x < 128) {
        as[threadIdx.x] = a_src[threadIdx.x];
        ad[threadIdx.x] = a_dst[threadIdx.x];
    }
    __syncthreads();
    int idx = blockIdx.x * 256 + threadIdx.x;
    if (idx >= NN * HH) return;
    int n = idx >> 3, h = idx & 7;
    const float* x = &xh[(size_t)n * DD + h * CC];
    float s1 = 0.f, s2 = 0.f;
#pragma unroll
    for (int c = 0; c < CC; c++) {
        float v = x[c];
        s1 += v * as[h * CC + c];
        s2 += v * ad[h * CC + c];
    }
    s_src[idx] = s1;
    s_dst[idx] = s2;
}

// ---------------- aggregation: one wave per destination node ----------------
__global__ __launch_bounds__(256) void agg_k(const int* __restrict__ row_start,
                                             const int* __restrict__ e_src,
                                             const float* __restrict__ s_src,
                                             const float* __restrict__ s_dst,
                                             const float* __restrict__ s_e,
                                             const float* __restrict__ xh,
                                             float* __restrict__ out) {
    int wid = (blockIdx.x * 256 + threadIdx.x) >> 6;
    if (wid >= NN) return;
    int lane = threadIdx.x & 63;
    int h = lane >> 3;
    float sdst = s_dst[wid * 8 + h];
    int beg = row_start[wid], end = row_start[wid + 1];
    float acc0 = 0.f, acc1 = 0.f, z = 0.f;
    for (int p = beg; p < end; p++) {
        int src = e_src[p];
        float a = s_src[src * 8 + h] + sdst + s_e[(size_t)p * 8 + h];
        a = (a > 0.f) ? a : 0.2f * a;
        float ex = __expf(a);
        float2 xv = *(const float2*)&xh[(size_t)src * DD + lane * 2];
        z += ex;
        acc0 = fmaf(ex, xv.x, acc0);
        acc1 = fmaf(ex, xv.y, acc1);
    }
    float inv = 1.f / (z + 1e-16f);
    *(float2*)&out[(size_t)wid * DD + lane * 2] = make_float2(acc0 * inv, acc1 * inv);
}

// ---------------- bias + LayerNorm(ddof=1) + leaky_relu(0.01) + residual ----------------
__global__ __launch_bounds__(256) void ln_k(const float* __restrict__ hin,
                                            const float* __restrict__ bias,
                                            const float* __restrict__ g,
                                            const float* __restrict__ be,
                                            const float* __restrict__ res,
                                            float* __restrict__ out) {
    int wid = (blockIdx.x * 256 + threadIdx.x) >> 6;
    if (wid >= NN) return;
    int lane = threadIdx.x & 63;
    float2 x = *(const float2*)&hin[(size_t)wid * DD + lane * 2];
    float2 b = *(const float2*)&bias[lane * 2];
    x.x += b.x;
    x.y += b.y;
    float s = x.x + x.y;
    float q = x.x * x.x + x.y * x.y;
#pragma unroll
    for (int m = 1; m < 64; m <<= 1) {
        s += __shfl_xor(s, m, 64);
        q += __shfl_xor(q, m, 64);
    }
    float mu = s * (1.f / 128.f);
    float var = (q - 128.f * mu * mu) * (1.f / 127.f);
    float sd = sqrtf(fmaxf(var, 0.f));
    float inv = 1.f / (sd + 1e-6f);
    float2 gg = *(const float2*)&g[lane * 2];
    float2 bb = *(const float2*)&be[lane * 2];
    float y0 = gg.x * (x.x - mu) * inv + bb.x;
    float y1 = gg.y * (x.y - mu) * inv + bb.y;
    y0 = (y0 > 0.f) ? y0 : 0.01f * y0;
    y1 = (y1 > 0.f) ? y1 : 0.01f * y1;
    float2 r = *(const float2*)&res[(size_t)wid * DD + lane * 2];
    *(float2*)&out[(size_t)wid * DD + lane * 2] = make_float2(r.x + y0, r.y + y1);
}

// ---------------- fused FFN: 16 nodes / block, hidden kept in LDS ----------------
// phase A: thread -> 2 hidden cols x 16 nodes; phase B: thread -> 2 out dims x 4 nodes
__global__ __launch_bounds__(256) void ffn_k(const float* __restrict__ X,
                                             const float* __restrict__ Wf1,
                                             const float* __restrict__ bf1,
                                             const float* __restrict__ Wf2,
                                             float* __restrict__ out) {
    __shared__ float xT[128][20];
    __shared__ float hT[512][20];
    int t = threadIdx.x;
    int nb0 = blockIdx.x * 16;
    for (int i = t; i < 16 * 128; i += 256) {
        int k = i & 127, nb = i >> 7;
        xT[k][nb] = X[(size_t)(nb0 + nb) * DD + k];
    }
    __syncthreads();
    // ---- phase A ----
    {
        float acc0[16], acc1[16];
#pragma unroll
        for (int i = 0; i < 16; i++) { acc0[i] = 0.f; acc1[i] = 0.f; }
        for (int k = 0; k < 128; k++) {
            float w0 = Wf1[(size_t)k * DFF + t];
            float w1 = Wf1[(size_t)k * DFF + t + 256];
            const float* xp = &xT[k][0];
            float4 a0 = *(const float4*)(xp);
            float4 a1 = *(const float4*)(xp + 4);
            float4 a2 = *(const float4*)(xp + 8);
            float4 a3 = *(const float4*)(xp + 12);
            float xs[16] = {a0.x, a0.y, a0.z, a0.w, a1.x, a1.y, a1.z, a1.w,
                            a2.x, a2.y, a2.z, a2.w, a3.x, a3.y, a3.z, a3.w};
#pragma unroll
            for (int i = 0; i < 16; i++) {
                acc0[i] = fmaf(w0, xs[i], acc0[i]);
                acc1[i] = fmaf(w1, xs[i], acc1[i]);
            }
        }
        float b0 = bf1[t];
        float b1 = bf1[t + 256];
#pragma unroll
        for (int i = 0; i < 16; i++) {
            acc0[i] = fmaxf(acc0[i] + b0, 0.f);
            acc1[i] = fmaxf(acc1[i] + b1, 0.f);
        }
#pragma unroll
        for (int j = 0; j < 4; j++) {
            *(float4*)&hT[t][j * 4]       = make_float4(acc0[j * 4], acc0[j * 4 + 1], acc0[j * 4 + 2], acc0[j * 4 + 3]);
            *(float4*)&hT[t + 256][j * 4] = make_float4(acc1[j * 4], acc1[j * 4 + 1], acc1[j * 4 + 2], acc1[j * 4 + 3]);
        }
    }
    __syncthreads();
    // ---- phase B ----
    {
        int d0 = (t & 63) * 2;
        int ngrp = t >> 6;  // wave-uniform
        float2 acc[4];
#pragma unroll
        for (int j = 0; j < 4; j++) acc[j] = make_float2(0.f, 0.f);
        for (int u = 0; u < 512; u++) {
            float2 w = *(const float2*)&Wf2[(size_t)u * DD + d0];
            float4 h = *(const float4*)&hT[u][ngrp * 4];
            float hs[4] = {h.x, h.y, h.z, h.w};
#pragma unroll
            for (int j = 0; j < 4; j++) {
                acc[j].x = fmaf(w.x, hs[j], acc[j].x);
                acc[j].y = fmaf(w.y, hs[j], acc[j].y);
            }
        }
#pragma unroll
        for (int j = 0; j < 4; j++) {
            int n = nb0 + ngrp * 4 + j;
            *(float2*)&out[(size_t)n * DD + d0] = acc[j];
        }
    }
}

extern "C" void kernel_launch(void* const* d_in, const int* in_sizes, int n_in,
                              void* d_out, int out_size, void* d_ws, size_t ws_size,
                              hipStream_t stream) {
    const float* nf  = (const float*)d_in[0];
    const int*   ei  = (const int*)d_in[1];
    const float* ew  = (const float*)d_in[2];
    const float* W1  = (const float*)d_in[3];
    const float* as1 = (const float*)d_in[4];
    const float* ad1 = (const float*)d_in[5];
    const float* We1 = (const float*)d_in[6];
    const float* ae1 = (const float*)d_in[7];
    const float* b1  = (const float*)d_in[8];
    const float* g1  = (const float*)d_in[9];
    const float* be1 = (const float*)d_in[10];
    const float* W2  = (const float*)d_in[11];
    const float* as2 = (const float*)d_in[12];
    const float* ad2 = (const float*)d_in[13];
    const float* We2 = (const float*)d_in[14];
    const float* ae2 = (const float*)d_in[15];
    const float* b2  = (const float*)d_in[16];
    const float* g2  = (const float*)d_in[17];
    const float* be2 = (const float*)d_in[18];
    const float* Wf1 = (const float*)d_in[19];
    const float* bf1 = (const float*)d_in[20];
    const float* Wf2 = (const float*)d_in[21];
    const float* bf2 = (const float*)d_in[22];
    const float* g3  = (const float*)d_in[23];
    const float* be3 = (const float*)d_in[24];
    float* out = (float*)d_out;

    char* p = (char*)d_ws;
    auto alloc = [&](size_t bytes) {
        char* r = p;
        p += (bytes + 255) & ~(size_t)255;
        return r;
    };
    float* nf_cur = (float*)alloc((size_t)NN * DD * 4);
    float* xh     = (float*)alloc((size_t)NN * DD * 4);
    float* h_out  = (float*)alloc((size_t)NN * DD * 4);
    float* s_e    = (float*)alloc((size_t)NE * HH * 4);
    float* s_src  = (float*)alloc((size_t)NN * HH * 4);
    float* s_dst  = (float*)alloc((size_t)NN * HH * 4);
    int* row_start = (int*)alloc((size_t)(NN + 1) * 4);
    int* cursor    = (int*)alloc((size_t)NN * 4);
    int* e_src     = (int*)alloc((size_t)NE * 4);
    int* perm      = (int*)alloc((size_t)NE * 4);

    int ebl = (NE + 255) / 256;
    int nbl = (NN + 255) / 256;

    // CSR build
    zero_int_k<<<nbl, 256, 0, stream>>>(cursor, NN);
    count_k<<<ebl, 256, 0, stream>>>(ei + NE, cursor);
    scan_k<<<1, 1024, 0, stream>>>(cursor, row_start);
    scatter_k<<<ebl, 256, 0, stream>>>(ei, cursor, e_src, perm);

    int gbl = (NN + 63) / 64;       // gemm blocks
    int wbl = (NN + 3) / 4;         // wave-per-node kernels: 4 nodes/block
    int sbl = (NN * HH + 255) / 256;

    // ---- GAT layer 1 ----
    se_k<<<ebl, 256, 0, stream>>>(ew, We1, ae1, perm, s_e);
    gemm_k<<<gbl, 256, 0, stream>>>(nf, W1, xh);
    ssd_k<<<sbl, 256, 0, stream>>>(xh, as1, ad1, s_src, s_dst);
    agg_k<<<wbl, 256, 0, stream>>>(row_start, e_src, s_src, s_dst, s_e, xh, h_out);
    ln_k<<<wbl, 256, 0, stream>>>(h_out, b1, g1, be1, nf, nf_cur);

    // ---- GAT layer 2 ----
    se_k<<<ebl, 256, 0, stream>>>(ew, We2, ae2, perm, s_e);
    gemm_k<<<gbl, 256, 0, stream>>>(nf_cur, W2, xh);
    ssd_k<<<sbl, 256, 0, stream>>>(xh, as2, ad2, s_src, s_dst);
    agg_k<<<wbl, 256, 0, stream>>>(row_start, e_src, s_src, s_dst, s_e, xh, h_out);
    ln_k<<<wbl, 256, 0, stream>>>(h_out, b2, g2, be2, nf_cur, nf_cur);

    // ---- FFN ----
    ffn_k<<<NN / 16, 256, 0, stream>>>(nf_cur, Wf1, bf1, Wf2, h_out);
    ln_k<<<wbl, 256, 0, stream>>>(h_out, bf2, g3, be3, nf_cur, out);
}

// Round 3
// 577.800 us; speedup vs baseline: 1.3902x; 1.3902x over previous
//
#include <hip/hip_runtime.h>
#include <hip/hip_bf16.h>

#define NN 50000
#define NE 800000
#define DD 128
#define HH 8
#define CC 16
#define DFF 512
#define ED 16

typedef __attribute__((ext_vector_type(8))) short bf16x8;
typedef __attribute__((ext_vector_type(4))) float f32x4;

union U8 { bf16x8 v; unsigned short s[8]; };

__device__ inline unsigned short f2bf(float f) {
    union { float f; unsigned u; } v; v.f = f;
    return (unsigned short)((v.u + 0x7fffu + ((v.u >> 16) & 1u)) >> 16);
}

// ---------------- utility ----------------
__global__ void zero_int_k(int* __restrict__ a, int n) {
    int i = blockIdx.x * 256 + threadIdx.x;
    if (i < n) a[i] = 0;
}

// transpose + cvt weights: in [K][Nc] f32 -> out [Nc][K] bf16
__global__ void cvtT_k(const float* __restrict__ in, unsigned short* __restrict__ outT,
                       int K, int Nc) {
    int idx = blockIdx.x * 256 + threadIdx.x;
    if (idx >= K * Nc) return;
    int n = idx / K, k = idx - n * K;
    outT[idx] = f2bf(in[(size_t)k * Nc + n]);
}

// ---------------- CSR build ----------------
__global__ void count_k(const int* __restrict__ dst, int* __restrict__ cnt) {
    int e = blockIdx.x * 256 + threadIdx.x;
    if (e < NE) atomicAdd(&cnt[dst[e]], 1);
}

__global__ void scan_k(int* __restrict__ cnt, int* __restrict__ row_start) {
    __shared__ int part[1024];
    int t = threadIdx.x;
    const int CH = (NN + 1023) / 1024;
    int lo = t * CH;
    int hi = lo + CH; if (hi > NN) hi = NN; if (lo > NN) lo = NN;
    int s = 0;
    for (int i = lo; i < hi; i++) s += cnt[i];
    part[t] = s;
    __syncthreads();
    for (int off = 1; off < 1024; off <<= 1) {
        int v = (t >= off) ? part[t - off] : 0;
        __syncthreads();
        part[t] += v;
        __syncthreads();
    }
    int run = part[t] - s;
    for (int i = lo; i < hi; i++) {
        int c = cnt[i];
        row_start[i] = run;
        cnt[i] = run;
        run += c;
    }
    if (t == 1023) row_start[NN] = part[1023];
}

__global__ void scatter_k(const int* __restrict__ ei, int* __restrict__ cursor,
                          int* __restrict__ e_src, int* __restrict__ perm) {
    int e = blockIdx.x * 256 + threadIdx.x;
    if (e >= NE) return;
    int s = ei[e];
    int d = ei[NE + e];
    int pos = atomicAdd(&cursor[d], 1);
    e_src[pos] = s;
    perm[e] = pos;
}

// ---------------- edge scores ----------------
__global__ void se_k(const float* __restrict__ ew, const float* __restrict__ We,
                     const float* __restrict__ ae, const int* __restrict__ perm,
                     float* __restrict__ s_e) {
    __shared__ float Ae[ED * HH];
    int t = threadIdx.x;
    if (t < ED * HH) {
        int k = t >> 3, h = t & 7;
        float s = 0.f;
#pragma unroll
        for (int c = 0; c < CC; c++) s += We[k * DD + h * CC + c] * ae[h * CC + c];
        Ae[t] = s;
    }
    __syncthreads();
    int e = blockIdx.x * 256 + t;
    if (e >= NE) return;
    const float* ep = &ew[(size_t)e * ED];
    float4 v0 = *(const float4*)(ep);
    float4 v1 = *(const float4*)(ep + 4);
    float4 v2 = *(const float4*)(ep + 8);
    float4 v3 = *(const float4*)(ep + 12);
    float ev[16] = {v0.x, v0.y, v0.z, v0.w, v1.x, v1.y, v1.z, v1.w,
                    v2.x, v2.y, v2.z, v2.w, v3.x, v3.y, v3.z, v3.w};
    float o[8] = {0, 0, 0, 0, 0, 0, 0, 0};
#pragma unroll
    for (int k = 0; k < 16; k++) {
        float v = ev[k];
#pragma unroll
        for (int h = 0; h < 8; h++) o[h] += v * Ae[k * 8 + h];
    }
    int pp = perm[e];
    *(float4*)&s_e[(size_t)pp * 8]     = make_float4(o[0], o[1], o[2], o[3]);
    *(float4*)&s_e[(size_t)pp * 8 + 4] = make_float4(o[4], o[5], o[6], o[7]);
}

// ---------------- MFMA node GEMM: Y = X @ W  (via WT bf16 [128][128]) ----------------
// block: 128 nodes x 128 cols, 4 waves, each wave 64x64 quadrant (4x4 tiles 16x16x32)
__global__ __launch_bounds__(256) void gemm_mfma_k(const float* __restrict__ X,
                                                   const unsigned short* __restrict__ WT,
                                                   float* __restrict__ Y) {
    __shared__ char Xl[128 * 256];  // bf16 [row][128], XOR-swizzled
    int t = threadIdx.x;
    int nb0 = blockIdx.x * 128;
    for (int c = t; c < 2048; c += 256) {
        int row = c >> 4, cb = c & 15;
        int n = nb0 + row;
        U8 u;
        if (n < NN) {
            const float* xp = &X[(size_t)n * DD + cb * 8];
            float4 a = *(const float4*)xp;
            float4 b = *(const float4*)(xp + 4);
            u.s[0] = f2bf(a.x); u.s[1] = f2bf(a.y); u.s[2] = f2bf(a.z); u.s[3] = f2bf(a.w);
            u.s[4] = f2bf(b.x); u.s[5] = f2bf(b.y); u.s[6] = f2bf(b.z); u.s[7] = f2bf(b.w);
        } else {
#pragma unroll
            for (int q = 0; q < 8; q++) u.s[q] = 0;
        }
        int byte = (row * 256 + cb * 16) ^ ((row & 7) << 4);
        *(bf16x8*)&Xl[byte] = u.v;
    }
    __syncthreads();
    int w = t >> 6, l = t & 63;
    int lrow = l & 15, lq = l >> 4;
    int r0 = (w & 1) * 64, c0 = (w >> 1) * 64;
    f32x4 acc[4][4];
#pragma unroll
    for (int i = 0; i < 4; i++)
#pragma unroll
        for (int j = 0; j < 4; j++) acc[i][j] = (f32x4){0.f, 0.f, 0.f, 0.f};
#pragma unroll
    for (int ks = 0; ks < 4; ks++) {
        int k0 = ks * 32;
        bf16x8 af[4], bq[4];
#pragma unroll
        for (int i = 0; i < 4; i++) {
            int rr = r0 + i * 16 + lrow;
            int byte = (rr * 256 + k0 * 2 + lq * 16) ^ ((rr & 7) << 4);
            af[i] = *(const bf16x8*)&Xl[byte];
        }
#pragma unroll
        for (int j = 0; j < 4; j++) {
            int cc = c0 + j * 16 + lrow;
            bq[j] = *(const bf16x8*)&WT[(size_t)cc * DD + k0 + lq * 8];
        }
#pragma unroll
        for (int i = 0; i < 4; i++)
#pragma unroll
            for (int j = 0; j < 4; j++)
                acc[i][j] = __builtin_amdgcn_mfma_f32_16x16x32_bf16(af[i], bq[j], acc[i][j], 0, 0, 0);
    }
#pragma unroll
    for (int i = 0; i < 4; i++) {
#pragma unroll
        for (int j = 0; j < 4; j++) {
#pragma unroll
            for (int q = 0; q < 4; q++) {
                int n = nb0 + r0 + i * 16 + lq * 4 + q;
                if (n < NN) Y[(size_t)n * DD + c0 + j * 16 + lrow] = acc[i][j][q];
            }
        }
    }
}

// ---------------- s_src/s_dst ----------------
__global__ void ssd_k(const float* __restrict__ xh, const float* __restrict__ a_src,
                      const float* __restrict__ a_dst, float* __restrict__ s_src,
                      float* __restrict__ s_dst) {
    __shared__ float as[128], ad[128];
    if (threadIdx.x < 128) {
        as[threadIdx.x] = a_src[threadIdx.x];
        ad[threadIdx.x] = a_dst[threadIdx.x];
    }
    __syncthreads();
    int idx = blockIdx.x * 256 + threadIdx.x;
    if (idx >= NN * HH) return;
    int n = idx >> 3, h = idx & 7;
    const float* x = &xh[(size_t)n * DD + h * CC];
    float s1 = 0.f, s2 = 0.f;
#pragma unroll
    for (int c = 0; c < CC; c++) {
        float v = x[c];
        s1 += v * as[h * CC + c];
        s2 += v * ad[h * CC + c];
    }
    s_src[idx] = s1;
    s_dst[idx] = s2;
}

// ---------------- aggregation: one wave per destination node ----------------
__global__ __launch_bounds__(256) void agg_k(const int* __restrict__ row_start,
                                             const int* __restrict__ e_src,
                                             const float* __restrict__ s_src,
                                             const float* __restrict__ s_dst,
                                             const float* __restrict__ s_e,
                                             const float* __restrict__ xh,
                                             float* __restrict__ out) {
    int wid = (blockIdx.x * 256 + threadIdx.x) >> 6;
    if (wid >= NN) return;
    int lane = threadIdx.x & 63;
    int h = lane >> 3;
    float sdst = s_dst[wid * 8 + h];
    int beg = row_start[wid], end = row_start[wid + 1];
    float acc0 = 0.f, acc1 = 0.f, z = 0.f;
    for (int p = beg; p < end; p++) {
        int src = e_src[p];
        float a = s_src[src * 8 + h] + sdst + s_e[(size_t)p * 8 + h];
        a = (a > 0.f) ? a : 0.2f * a;
        float ex = __expf(a);
        float2 xv = *(const float2*)&xh[(size_t)src * DD + lane * 2];
        z += ex;
        acc0 = fmaf(ex, xv.x, acc0);
        acc1 = fmaf(ex, xv.y, acc1);
    }
    float inv = 1.f / (z + 1e-16f);
    *(float2*)&out[(size_t)wid * DD + lane * 2] = make_float2(acc0 * inv, acc1 * inv);
}

// ---------------- bias + LayerNorm(ddof=1) + leaky_relu + residual ----------------
__global__ __launch_bounds__(256) void ln_k(const float* __restrict__ hin,
                                            const float* __restrict__ bias,
                                            const float* __restrict__ g,
                                            const float* __restrict__ be,
                                            const float* __restrict__ res,
                                            float* __restrict__ out) {
    int wid = (blockIdx.x * 256 + threadIdx.x) >> 6;
    if (wid >= NN) return;
    int lane = threadIdx.x & 63;
    float2 x = *(const float2*)&hin[(size_t)wid * DD + lane * 2];
    float2 b = *(const float2*)&bias[lane * 2];
    x.x += b.x;
    x.y += b.y;
    float s = x.x + x.y;
    float q = x.x * x.x + x.y * x.y;
#pragma unroll
    for (int m = 1; m < 64; m <<= 1) {
        s += __shfl_xor(s, m, 64);
        q += __shfl_xor(q, m, 64);
    }
    float mu = s * (1.f / 128.f);
    float var = (q - 128.f * mu * mu) * (1.f / 127.f);
    float sd = sqrtf(fmaxf(var, 0.f));
    float inv = 1.f / (sd + 1e-6f);
    float2 gg = *(const float2*)&g[lane * 2];
    float2 bb = *(const float2*)&be[lane * 2];
    float y0 = gg.x * (x.x - mu) * inv + bb.x;
    float y1 = gg.y * (x.y - mu) * inv + bb.y;
    y0 = (y0 > 0.f) ? y0 : 0.01f * y0;
    y1 = (y1 > 0.f) ? y1 : 0.01f * y1;
    float2 r = *(const float2*)&res[(size_t)wid * DD + lane * 2];
    *(float2*)&out[(size_t)wid * DD + lane * 2] = make_float2(r.x + y0, r.y + y1);
}

// ---------------- fused MFMA FFN: 32 nodes/block ----------------
// phase A: H = relu(X@Wf1 + b1) -> bf16 LDS; phase B: out = H@Wf2 (f32)
__global__ __launch_bounds__(256) void ffn_mfma_k(const float* __restrict__ X,
                                                  const unsigned short* __restrict__ Wf1T,
                                                  const float* __restrict__ bf1,
                                                  const unsigned short* __restrict__ Wf2T,
                                                  float* __restrict__ out) {
    __shared__ char Xl[32 * 256];    // bf16 [32][128] swizzled
    __shared__ char Hl[32 * 1024];   // bf16 [32][512] swizzled
    int t = threadIdx.x;
    int nb0 = blockIdx.x * 32;
    for (int c = t; c < 512; c += 256) {
        int row = c >> 4, cb = c & 15;
        int n = nb0 + row;
        U8 u;
        if (n < NN) {
            const float* xp = &X[(size_t)n * DD + cb * 8];
            float4 a = *(const float4*)xp;
            float4 b = *(const float4*)(xp + 4);
            u.s[0] = f2bf(a.x); u.s[1] = f2bf(a.y); u.s[2] = f2bf(a.z); u.s[3] = f2bf(a.w);
            u.s[4] = f2bf(b.x); u.s[5] = f2bf(b.y); u.s[6] = f2bf(b.z); u.s[7] = f2bf(b.w);
        } else {
#pragma unroll
            for (int q = 0; q < 8; q++) u.s[q] = 0;
        }
        int byte = (row * 256 + cb * 16) ^ ((row & 7) << 4);
        *(bf16x8*)&Xl[byte] = u.v;
    }
    __syncthreads();
    int w = t >> 6, l = t & 63;
    int lrow = l & 15, lq = l >> 4;
    // ---- phase A: wave w covers hidden cols u0..u0+127 ----
    {
        int u0 = w * 128;
        f32x4 acc[2][8];
#pragma unroll
        for (int i = 0; i < 2; i++)
#pragma unroll
            for (int j = 0; j < 8; j++) acc[i][j] = (f32x4){0.f, 0.f, 0.f, 0.f};
#pragma unroll
        for (int ks = 0; ks < 4; ks++) {
            int k0 = ks * 32;
            bf16x8 af[2], bq[8];
#pragma unroll
            for (int i = 0; i < 2; i++) {
                int rr = i * 16 + lrow;
                int byte = (rr * 256 + k0 * 2 + lq * 16) ^ ((rr & 7) << 4);
                af[i] = *(const bf16x8*)&Xl[byte];
            }
#pragma unroll
            for (int j = 0; j < 8; j++) {
                int cc = u0 + j * 16 + lrow;
                bq[j] = *(const bf16x8*)&Wf1T[(size_t)cc * DD + k0 + lq * 8];
            }
#pragma unroll
            for (int i = 0; i < 2; i++)
#pragma unroll
                for (int j = 0; j < 8; j++)
                    acc[i][j] = __builtin_amdgcn_mfma_f32_16x16x32_bf16(af[i], bq[j], acc[i][j], 0, 0, 0);
        }
        float bias[8];
#pragma unroll
        for (int j = 0; j < 8; j++) bias[j] = bf1[u0 + j * 16 + lrow];
#pragma unroll
        for (int i = 0; i < 2; i++) {
#pragma unroll
            for (int j = 0; j < 8; j++) {
#pragma unroll
                for (int q = 0; q < 4; q++) {
                    float v = acc[i][j][q] + bias[j];
                    v = fmaxf(v, 0.f);
                    int row = i * 16 + lq * 4 + q;
                    int col = u0 + j * 16 + lrow;
                    int byte = (row * 1024 + col * 2) ^ ((row & 7) << 4);
                    *(unsigned short*)&Hl[byte] = f2bf(v);
                }
            }
        }
    }
    __syncthreads();
    // ---- phase B: wave w covers out cols c0..c0+31 ----
    {
        int c0 = w * 32;
        f32x4 acc2[2][2];
#pragma unroll
        for (int i = 0; i < 2; i++)
#pragma unroll
            for (int j = 0; j < 2; j++) acc2[i][j] = (f32x4){0.f, 0.f, 0.f, 0.f};
        for (int ks = 0; ks < 16; ks++) {
            int k0 = ks * 32;
            bf16x8 af[2], bq[2];
#pragma unroll
            for (int i = 0; i < 2; i++) {
                int rr = i * 16 + lrow;
                int byte = (rr * 1024 + k0 * 2 + lq * 16) ^ ((rr & 7) << 4);
                af[i] = *(const bf16x8*)&Hl[byte];
            }
#pragma unroll
            for (int j = 0; j < 2; j++) {
                int cc = c0 + j * 16 + lrow;
                bq[j] = *(const bf16x8*)&Wf2T[(size_t)cc * DFF + k0 + lq * 8];
            }
#pragma unroll
            for (int i = 0; i < 2; i++)
#pragma unroll
                for (int j = 0; j < 2; j++)
                    acc2[i][j] = __builtin_amdgcn_mfma_f32_16x16x32_bf16(af[i], bq[j], acc2[i][j], 0, 0, 0);
        }
#pragma unroll
        for (int i = 0; i < 2; i++) {
#pragma unroll
            for (int j = 0; j < 2; j++) {
#pragma unroll
                for (int q = 0; q < 4; q++) {
                    int n = nb0 + i * 16 + lq * 4 + q;
                    if (n < NN) out[(size_t)n * DD + c0 + j * 16 + lrow] = acc2[i][j][q];
                }
            }
        }
    }
}

extern "C" void kernel_launch(void* const* d_in, const int* in_sizes, int n_in,
                              void* d_out, int out_size, void* d_ws, size_t ws_size,
                              hipStream_t stream) {
    const float* nf  = (const float*)d_in[0];
    const int*   ei  = (const int*)d_in[1];
    const float* ew  = (const float*)d_in[2];
    const float* W1  = (const float*)d_in[3];
    const float* as1 = (const float*)d_in[4];
    const float* ad1 = (const float*)d_in[5];
    const float* We1 = (const float*)d_in[6];
    const float* ae1 = (const float*)d_in[7];
    const float* b1  = (const float*)d_in[8];
    const float* g1  = (const float*)d_in[9];
    const float* be1 = (const float*)d_in[10];
    const float* W2  = (const float*)d_in[11];
    const float* as2 = (const float*)d_in[12];
    const float* ad2 = (const float*)d_in[13];
    const float* We2 = (const float*)d_in[14];
    const float* ae2 = (const float*)d_in[15];
    const float* b2  = (const float*)d_in[16];
    const float* g2  = (const float*)d_in[17];
    const float* be2 = (const float*)d_in[18];
    const float* Wf1 = (const float*)d_in[19];
    const float* bf1 = (const float*)d_in[20];
    const float* Wf2 = (const float*)d_in[21];
    const float* bf2 = (const float*)d_in[22];
    const float* g3  = (const float*)d_in[23];
    const float* be3 = (const float*)d_in[24];
    float* out = (float*)d_out;

    char* p = (char*)d_ws;
    auto alloc = [&](size_t bytes) {
        char* r = p;
        p += (bytes + 255) & ~(size_t)255;
        return r;
    };
    float* nf_cur = (float*)alloc((size_t)NN * DD * 4);
    float* xh     = (float*)alloc((size_t)NN * DD * 4);
    float* h_out  = (float*)alloc((size_t)NN * DD * 4);
    float* s_e    = (float*)alloc((size_t)NE * HH * 4);
    float* s_src  = (float*)alloc((size_t)NN * HH * 4);
    float* s_dst  = (float*)alloc((size_t)NN * HH * 4);
    int* row_start = (int*)alloc((size_t)(NN + 1) * 4);
    int* cursor    = (int*)alloc((size_t)NN * 4);
    int* e_src     = (int*)alloc((size_t)NE * 4);
    int* perm      = (int*)alloc((size_t)NE * 4);
    unsigned short* W1T  = (unsigned short*)alloc((size_t)DD * DD * 2);
    unsigned short* W2T  = (unsigned short*)alloc((size_t)DD * DD * 2);
    unsigned short* Wf1T = (unsigned short*)alloc((size_t)DFF * DD * 2);
    unsigned short* Wf2T = (unsigned short*)alloc((size_t)DD * DFF * 2);

    int ebl = (NE + 255) / 256;
    int nbl = (NN + 255) / 256;

    // weight transpose+cvt (tiny, once)
    cvtT_k<<<(DD * DD + 255) / 256, 256, 0, stream>>>(W1, W1T, DD, DD);
    cvtT_k<<<(DD * DD + 255) / 256, 256, 0, stream>>>(W2, W2T, DD, DD);
    cvtT_k<<<(DD * DFF + 255) / 256, 256, 0, stream>>>(Wf1, Wf1T, DD, DFF);   // [512][128]
    cvtT_k<<<(DD * DFF + 255) / 256, 256, 0, stream>>>(Wf2, Wf2T, DFF, DD);   // [128][512]

    // CSR build
    zero_int_k<<<nbl, 256, 0, stream>>>(cursor, NN);
    count_k<<<ebl, 256, 0, stream>>>(ei + NE, cursor);
    scan_k<<<1, 1024, 0, stream>>>(cursor, row_start);
    scatter_k<<<ebl, 256, 0, stream>>>(ei, cursor, e_src, perm);

    int gbl = (NN + 127) / 128;
    int wbl = (NN + 3) / 4;
    int sbl = (NN * HH + 255) / 256;

    // ---- GAT layer 1 ----
    se_k<<<ebl, 256, 0, stream>>>(ew, We1, ae1, perm, s_e);
    gemm_mfma_k<<<gbl, 256, 0, stream>>>(nf, W1T, xh);
    ssd_k<<<sbl, 256, 0, stream>>>(xh, as1, ad1, s_src, s_dst);
    agg_k<<<wbl, 256, 0, stream>>>(row_start, e_src, s_src, s_dst, s_e, xh, h_out);
    ln_k<<<wbl, 256, 0, stream>>>(h_out, b1, g1, be1, nf, nf_cur);

    // ---- GAT layer 2 ----
    se_k<<<ebl, 256, 0, stream>>>(ew, We2, ae2, perm, s_e);
    gemm_mfma_k<<<gbl, 256, 0, stream>>>(nf_cur, W2T, xh);
    ssd_k<<<sbl, 256, 0, stream>>>(xh, as2, ad2, s_src, s_dst);
    agg_k<<<wbl, 256, 0, stream>>>(row_start, e_src, s_src, s_dst, s_e, xh, h_out);
    ln_k<<<wbl, 256, 0, stream>>>(h_out, b2, g2, be2, nf_cur, nf_cur);

    // ---- FFN ----
    ffn_mfma_k<<<(NN + 31) / 32, 256, 0, stream>>>(nf_cur, Wf1T, bf1, Wf2T, h_out);
    ln_k<<<wbl, 256, 0, stream>>>(h_out, bf2, g3, be3, nf_cur, out);
}

// Round 4
// 476.473 us; speedup vs baseline: 1.6859x; 1.2127x over previous
//
#include <hip/hip_runtime.h>
#include <hip/hip_bf16.h>

#define NN 50000
#define NE 800000
#define DD 128
#define HH 8
#define CC 16
#define DFF 512
#define ED 16
#define SCAN_NB ((NN + 255) / 256)   // 196

typedef __attribute__((ext_vector_type(8))) short bf16x8;
typedef __attribute__((ext_vector_type(4))) float f32x4;

union U8 { bf16x8 v; unsigned short s[8]; };

__device__ inline unsigned short f2bf(float f) {
    union { float f; unsigned u; } v; v.f = f;
    return (unsigned short)((v.u + 0x7fffu + ((v.u >> 16) & 1u)) >> 16);
}

// ---------------- utility ----------------
__global__ void zero_int_k(int* __restrict__ a, int n) {
    int i = blockIdx.x * 256 + threadIdx.x;
    if (i < n) a[i] = 0;
}

// transpose + cvt weights: in [K][Nc] f32 -> out [Nc][K] bf16
__global__ void cvtT_k(const float* __restrict__ in, unsigned short* __restrict__ outT,
                       int K, int Nc) {
    int idx = blockIdx.x * 256 + threadIdx.x;
    if (idx >= K * Nc) return;
    int n = idx / K, k = idx - n * K;
    outT[idx] = f2bf(in[(size_t)k * Nc + n]);
}

// ---------------- CSR build ----------------
__global__ void count_k(const int* __restrict__ dst, int* __restrict__ cnt) {
    int e = blockIdx.x * 256 + threadIdx.x;
    if (e < NE) atomicAdd(&cnt[dst[e]], 1);
}

// hierarchical scan: per-block sums
__global__ void blksum_k(const int* __restrict__ cnt, int* __restrict__ partials) {
    int i = blockIdx.x * 256 + threadIdx.x;
    int v = (i < NN) ? cnt[i] : 0;
#pragma unroll
    for (int m = 1; m < 64; m <<= 1) v += __shfl_xor(v, m, 64);
    __shared__ int ws[4];
    if ((threadIdx.x & 63) == 0) ws[threadIdx.x >> 6] = v;
    __syncthreads();
    if (threadIdx.x == 0) partials[blockIdx.x] = ws[0] + ws[1] + ws[2] + ws[3];
}

// exclusive scan of partials (1 block)
__global__ void scanpart_k(int* __restrict__ partials) {
    __shared__ int buf[256];
    int t = threadIdx.x;
    int v = (t < SCAN_NB) ? partials[t] : 0;
    buf[t] = v;
    __syncthreads();
    for (int off = 1; off < 256; off <<= 1) {
        int u = (t >= off) ? buf[t - off] : 0;
        __syncthreads();
        buf[t] += u;
        __syncthreads();
    }
    if (t < SCAN_NB) partials[t] = buf[t] - v;  // exclusive
}

// block-local exclusive scan + offset -> row_start, cursor
__global__ void scanapply_k(const int* __restrict__ cnt, const int* __restrict__ partials,
                            int* __restrict__ row_start, int* __restrict__ cursor) {
    __shared__ int buf[256];
    int t = threadIdx.x;
    int i = blockIdx.x * 256 + t;
    int v = (i < NN) ? cnt[i] : 0;
    buf[t] = v;
    __syncthreads();
    for (int off = 1; off < 256; off <<= 1) {
        int u = (t >= off) ? buf[t - off] : 0;
        __syncthreads();
        buf[t] += u;
        __syncthreads();
    }
    int excl = buf[t] - v + partials[blockIdx.x];
    if (i < NN) {
        row_start[i] = excl;
        cursor[i] = excl;
        if (i == NN - 1) row_start[NN] = excl + v;
    }
}

__global__ void scatter_k(const int* __restrict__ ei, int* __restrict__ cursor,
                          int* __restrict__ e_src, int* __restrict__ perm) {
    int e = blockIdx.x * 256 + threadIdx.x;
    if (e >= NE) return;
    int s = ei[e];
    int d = ei[NE + e];
    int pos = atomicAdd(&cursor[d], 1);
    e_src[pos] = s;
    perm[e] = pos;
}

// ---------------- edge scores ----------------
__global__ void se_k(const float* __restrict__ ew, const float* __restrict__ We,
                     const float* __restrict__ ae, const int* __restrict__ perm,
                     float* __restrict__ s_e) {
    __shared__ float Ae[ED * HH];
    int t = threadIdx.x;
    if (t < ED * HH) {
        int k = t >> 3, h = t & 7;
        float s = 0.f;
#pragma unroll
        for (int c = 0; c < CC; c++) s += We[k * DD + h * CC + c] * ae[h * CC + c];
        Ae[t] = s;
    }
    __syncthreads();
    int e = blockIdx.x * 256 + t;
    if (e >= NE) return;
    const float* ep = &ew[(size_t)e * ED];
    float4 v0 = *(const float4*)(ep);
    float4 v1 = *(const float4*)(ep + 4);
    float4 v2 = *(const float4*)(ep + 8);
    float4 v3 = *(const float4*)(ep + 12);
    float ev[16] = {v0.x, v0.y, v0.z, v0.w, v1.x, v1.y, v1.z, v1.w,
                    v2.x, v2.y, v2.z, v2.w, v3.x, v3.y, v3.z, v3.w};
    float o[8] = {0, 0, 0, 0, 0, 0, 0, 0};
#pragma unroll
    for (int k = 0; k < 16; k++) {
        float v = ev[k];
#pragma unroll
        for (int h = 0; h < 8; h++) o[h] += v * Ae[k * 8 + h];
    }
    int pp = perm[e];
    *(float4*)&s_e[(size_t)pp * 8]     = make_float4(o[0], o[1], o[2], o[3]);
    *(float4*)&s_e[(size_t)pp * 8 + 4] = make_float4(o[4], o[5], o[6], o[7]);
}

// ---------------- MFMA node GEMM: Y = X @ W  (via WT bf16 [128][128]) ----------------
__global__ __launch_bounds__(256) void gemm_mfma_k(const float* __restrict__ X,
                                                   const unsigned short* __restrict__ WT,
                                                   float* __restrict__ Y) {
    __shared__ char Xl[128 * 256];  // bf16 [row][128], XOR-swizzled
    int t = threadIdx.x;
    int nb0 = blockIdx.x * 128;
    for (int c = t; c < 2048; c += 256) {
        int row = c >> 4, cb = c & 15;
        int n = nb0 + row;
        U8 u;
        if (n < NN) {
            const float* xp = &X[(size_t)n * DD + cb * 8];
            float4 a = *(const float4*)xp;
            float4 b = *(const float4*)(xp + 4);
            u.s[0] = f2bf(a.x); u.s[1] = f2bf(a.y); u.s[2] = f2bf(a.z); u.s[3] = f2bf(a.w);
            u.s[4] = f2bf(b.x); u.s[5] = f2bf(b.y); u.s[6] = f2bf(b.z); u.s[7] = f2bf(b.w);
        } else {
#pragma unroll
            for (int q = 0; q < 8; q++) u.s[q] = 0;
        }
        int byte = (row * 256 + cb * 16) ^ ((row & 7) << 4);
        *(bf16x8*)&Xl[byte] = u.v;
    }
    __syncthreads();
    int w = t >> 6, l = t & 63;
    int lrow = l & 15, lq = l >> 4;
    int r0 = (w & 1) * 64, c0 = (w >> 1) * 64;
    f32x4 acc[4][4];
#pragma unroll
    for (int i = 0; i < 4; i++)
#pragma unroll
        for (int j = 0; j < 4; j++) acc[i][j] = (f32x4){0.f, 0.f, 0.f, 0.f};
#pragma unroll
    for (int ks = 0; ks < 4; ks++) {
        int k0 = ks * 32;
        bf16x8 af[4], bq[4];
#pragma unroll
        for (int i = 0; i < 4; i++) {
            int rr = r0 + i * 16 + lrow;
            int byte = (rr * 256 + k0 * 2 + lq * 16) ^ ((rr & 7) << 4);
            af[i] = *(const bf16x8*)&Xl[byte];
        }
#pragma unroll
        for (int j = 0; j < 4; j++) {
            int cc = c0 + j * 16 + lrow;
            bq[j] = *(const bf16x8*)&WT[(size_t)cc * DD + k0 + lq * 8];
        }
#pragma unroll
        for (int i = 0; i < 4; i++)
#pragma unroll
            for (int j = 0; j < 4; j++)
                acc[i][j] = __builtin_amdgcn_mfma_f32_16x16x32_bf16(af[i], bq[j], acc[i][j], 0, 0, 0);
    }
#pragma unroll
    for (int i = 0; i < 4; i++) {
#pragma unroll
        for (int j = 0; j < 4; j++) {
#pragma unroll
            for (int q = 0; q < 4; q++) {
                int n = nb0 + r0 + i * 16 + lq * 4 + q;
                if (n < NN) Y[(size_t)n * DD + c0 + j * 16 + lrow] = acc[i][j][q];
            }
        }
    }
}

// ---------------- s_src/s_dst ----------------
__global__ void ssd_k(const float* __restrict__ xh, const float* __restrict__ a_src,
                      const float* __restrict__ a_dst, float* __restrict__ s_src,
                      float* __restrict__ s_dst) {
    __shared__ float as[128], ad[128];
    if (threadIdx.x < 128) {
        as[threadIdx.x] = a_src[threadIdx.x];
        ad[threadIdx.x] = a_dst[threadIdx.x];
    }
    __syncthreads();
    int idx = blockIdx.x * 256 + threadIdx.x;
    if (idx >= NN * HH) return;
    int n = idx >> 3, h = idx & 7;
    const float* x = &xh[(size_t)n * DD + h * CC];
    float s1 = 0.f, s2 = 0.f;
#pragma unroll
    for (int c = 0; c < CC; c++) {
        float v = x[c];
        s1 += v * as[h * CC + c];
        s2 += v * ad[h * CC + c];
    }
    s_src[idx] = s1;
    s_dst[idx] = s2;
}

// ---------------- aggregation: one wave per destination node ----------------
__global__ __launch_bounds__(256) void agg_k(const int* __restrict__ row_start,
                                             const int* __restrict__ e_src,
                                             const float* __restrict__ s_src,
                                             const float* __restrict__ s_dst,
                                             const float* __restrict__ s_e,
                                             const float* __restrict__ xh,
                                             float* __restrict__ out) {
    int wid = (blockIdx.x * 256 + threadIdx.x) >> 6;
    if (wid >= NN) return;
    int lane = threadIdx.x & 63;
    int h = lane >> 3;
    float sdst = s_dst[wid * 8 + h];
    int beg = row_start[wid], end = row_start[wid + 1];
    float acc0 = 0.f, acc1 = 0.f, z = 0.f;
    for (int p = beg; p < end; p++) {
        int src = e_src[p];
        float a = s_src[src * 8 + h] + sdst + s_e[(size_t)p * 8 + h];
        a = (a > 0.f) ? a : 0.2f * a;
        float ex = __expf(a);
        float2 xv = *(const float2*)&xh[(size_t)src * DD + lane * 2];
        z += ex;
        acc0 = fmaf(ex, xv.x, acc0);
        acc1 = fmaf(ex, xv.y, acc1);
    }
    float inv = 1.f / (z + 1e-16f);
    *(float2*)&out[(size_t)wid * DD + lane * 2] = make_float2(acc0 * inv, acc1 * inv);
}

// ---------------- bias + LayerNorm(ddof=1) + leaky_relu + residual ----------------
__global__ __launch_bounds__(256) void ln_k(const float* __restrict__ hin,
                                            const float* __restrict__ bias,
                                            const float* __restrict__ g,
                                            const float* __restrict__ be,
                                            const float* __restrict__ res,
                                            float* __restrict__ out) {
    int wid = (blockIdx.x * 256 + threadIdx.x) >> 6;
    if (wid >= NN) return;
    int lane = threadIdx.x & 63;
    float2 x = *(const float2*)&hin[(size_t)wid * DD + lane * 2];
    float2 b = *(const float2*)&bias[lane * 2];
    x.x += b.x;
    x.y += b.y;
    float s = x.x + x.y;
    float q = x.x * x.x + x.y * x.y;
#pragma unroll
    for (int m = 1; m < 64; m <<= 1) {
        s += __shfl_xor(s, m, 64);
        q += __shfl_xor(q, m, 64);
    }
    float mu = s * (1.f / 128.f);
    float var = (q - 128.f * mu * mu) * (1.f / 127.f);
    float sd = sqrtf(fmaxf(var, 0.f));
    float inv = 1.f / (sd + 1e-6f);
    float2 gg = *(const float2*)&g[lane * 2];
    float2 bb = *(const float2*)&be[lane * 2];
    float y0 = gg.x * (x.x - mu) * inv + bb.x;
    float y1 = gg.y * (x.y - mu) * inv + bb.y;
    y0 = (y0 > 0.f) ? y0 : 0.01f * y0;
    y1 = (y1 > 0.f) ? y1 : 0.01f * y1;
    float2 r = *(const float2*)&res[(size_t)wid * DD + lane * 2];
    *(float2*)&out[(size_t)wid * DD + lane * 2] = make_float2(r.x + y0, r.y + y1);
}

// ---------------- fused MFMA FFN: 32 nodes/block ----------------
__global__ __launch_bounds__(256) void ffn_mfma_k(const float* __restrict__ X,
                                                  const unsigned short* __restrict__ Wf1T,
                                                  const float* __restrict__ bf1,
                                                  const unsigned short* __restrict__ Wf2T,
                                                  float* __restrict__ out) {
    __shared__ char Xl[32 * 256];    // bf16 [32][128] swizzled
    __shared__ char Hl[32 * 1024];   // bf16 [32][512] swizzled
    int t = threadIdx.x;
    int nb0 = blockIdx.x * 32;
    for (int c = t; c < 512; c += 256) {
        int row = c >> 4, cb = c & 15;
        int n = nb0 + row;
        U8 u;
        if (n < NN) {
            const float* xp = &X[(size_t)n * DD + cb * 8];
            float4 a = *(const float4*)xp;
            float4 b = *(const float4*)(xp + 4);
            u.s[0] = f2bf(a.x); u.s[1] = f2bf(a.y); u.s[2] = f2bf(a.z); u.s[3] = f2bf(a.w);
            u.s[4] = f2bf(b.x); u.s[5] = f2bf(b.y); u.s[6] = f2bf(b.z); u.s[7] = f2bf(b.w);
        } else {
#pragma unroll
            for (int q = 0; q < 8; q++) u.s[q] = 0;
        }
        int byte = (row * 256 + cb * 16) ^ ((row & 7) << 4);
        *(bf16x8*)&Xl[byte] = u.v;
    }
    __syncthreads();
    int w = t >> 6, l = t & 63;
    int lrow = l & 15, lq = l >> 4;
    // ---- phase A ----
    {
        int u0 = w * 128;
        f32x4 acc[2][8];
#pragma unroll
        for (int i = 0; i < 2; i++)
#pragma unroll
            for (int j = 0; j < 8; j++) acc[i][j] = (f32x4){0.f, 0.f, 0.f, 0.f};
#pragma unroll
        for (int ks = 0; ks < 4; ks++) {
            int k0 = ks * 32;
            bf16x8 af[2], bq[8];
#pragma unroll
            for (int i = 0; i < 2; i++) {
                int rr = i * 16 + lrow;
                int byte = (rr * 256 + k0 * 2 + lq * 16) ^ ((rr & 7) << 4);
                af[i] = *(const bf16x8*)&Xl[byte];
            }
#pragma unroll
            for (int j = 0; j < 8; j++) {
                int cc = u0 + j * 16 + lrow;
                bq[j] = *(const bf16x8*)&Wf1T[(size_t)cc * DD + k0 + lq * 8];
            }
#pragma unroll
            for (int i = 0; i < 2; i++)
#pragma unroll
                for (int j = 0; j < 8; j++)
                    acc[i][j] = __builtin_amdgcn_mfma_f32_16x16x32_bf16(af[i], bq[j], acc[i][j], 0, 0, 0);
        }
        float bias[8];
#pragma unroll
        for (int j = 0; j < 8; j++) bias[j] = bf1[u0 + j * 16 + lrow];
#pragma unroll
        for (int i = 0; i < 2; i++) {
#pragma unroll
            for (int j = 0; j < 8; j++) {
#pragma unroll
                for (int q = 0; q < 4; q++) {
                    float v = acc[i][j][q] + bias[j];
                    v = fmaxf(v, 0.f);
                    int row = i * 16 + lq * 4 + q;
                    int col = u0 + j * 16 + lrow;
                    int byte = (row * 1024 + col * 2) ^ ((row & 7) << 4);
                    *(unsigned short*)&Hl[byte] = f2bf(v);
                }
            }
        }
    }
    __syncthreads();
    // ---- phase B ----
    {
        int c0 = w * 32;
        f32x4 acc2[2][2];
#pragma unroll
        for (int i = 0; i < 2; i++)
#pragma unroll
            for (int j = 0; j < 2; j++) acc2[i][j] = (f32x4){0.f, 0.f, 0.f, 0.f};
        for (int ks = 0; ks < 16; ks++) {
            int k0 = ks * 32;
            bf16x8 af[2], bq[2];
#pragma unroll
            for (int i = 0; i < 2; i++) {
                int rr = i * 16 + lrow;
                int byte = (rr * 1024 + k0 * 2 + lq * 16) ^ ((rr & 7) << 4);
                af[i] = *(const bf16x8*)&Hl[byte];
            }
#pragma unroll
            for (int j = 0; j < 2; j++) {
                int cc = c0 + j * 16 + lrow;
                bq[j] = *(const bf16x8*)&Wf2T[(size_t)cc * DFF + k0 + lq * 8];
            }
#pragma unroll
            for (int i = 0; i < 2; i++)
#pragma unroll
                for (int j = 0; j < 2; j++)
                    acc2[i][j] = __builtin_amdgcn_mfma_f32_16x16x32_bf16(af[i], bq[j], acc2[i][j], 0, 0, 0);
        }
#pragma unroll
        for (int i = 0; i < 2; i++) {
#pragma unroll
            for (int j = 0; j < 2; j++) {
#pragma unroll
                for (int q = 0; q < 4; q++) {
                    int n = nb0 + i * 16 + lq * 4 + q;
                    if (n < NN) out[(size_t)n * DD + c0 + j * 16 + lrow] = acc2[i][j][q];
                }
            }
        }
    }
}

extern "C" void kernel_launch(void* const* d_in, const int* in_sizes, int n_in,
                              void* d_out, int out_size, void* d_ws, size_t ws_size,
                              hipStream_t stream) {
    const float* nf  = (const float*)d_in[0];
    const int*   ei  = (const int*)d_in[1];
    const float* ew  = (const float*)d_in[2];
    const float* W1  = (const float*)d_in[3];
    const float* as1 = (const float*)d_in[4];
    const float* ad1 = (const float*)d_in[5];
    const float* We1 = (const float*)d_in[6];
    const float* ae1 = (const float*)d_in[7];
    const float* b1  = (const float*)d_in[8];
    const float* g1  = (const float*)d_in[9];
    const float* be1 = (const float*)d_in[10];
    const float* W2  = (const float*)d_in[11];
    const float* as2 = (const float*)d_in[12];
    const float* ad2 = (const float*)d_in[13];
    const float* We2 = (const float*)d_in[14];
    const float* ae2 = (const float*)d_in[15];
    const float* b2  = (const float*)d_in[16];
    const float* g2  = (const float*)d_in[17];
    const float* be2 = (const float*)d_in[18];
    const float* Wf1 = (const float*)d_in[19];
    const float* bf1 = (const float*)d_in[20];
    const float* Wf2 = (const float*)d_in[21];
    const float* bf2 = (const float*)d_in[22];
    const float* g3  = (const float*)d_in[23];
    const float* be3 = (const float*)d_in[24];
    float* out = (float*)d_out;

    char* p = (char*)d_ws;
    auto alloc = [&](size_t bytes) {
        char* r = p;
        p += (bytes + 255) & ~(size_t)255;
        return r;
    };
    float* nf_cur = (float*)alloc((size_t)NN * DD * 4);
    float* xh     = (float*)alloc((size_t)NN * DD * 4);
    float* h_out  = (float*)alloc((size_t)NN * DD * 4);
    float* s_e    = (float*)alloc((size_t)NE * HH * 4);
    float* s_src  = (float*)alloc((size_t)NN * HH * 4);
    float* s_dst  = (float*)alloc((size_t)NN * HH * 4);
    int* row_start = (int*)alloc((size_t)(NN + 1) * 4);
    int* cnt       = (int*)alloc((size_t)NN * 4);
    int* cursor    = (int*)alloc((size_t)NN * 4);
    int* partials  = (int*)alloc((size_t)SCAN_NB * 4);
    int* e_src     = (int*)alloc((size_t)NE * 4);
    int* perm      = (int*)alloc((size_t)NE * 4);
    unsigned short* W1T  = (unsigned short*)alloc((size_t)DD * DD * 2);
    unsigned short* W2T  = (unsigned short*)alloc((size_t)DD * DD * 2);
    unsigned short* Wf1T = (unsigned short*)alloc((size_t)DFF * DD * 2);
    unsigned short* Wf2T = (unsigned short*)alloc((size_t)DD * DFF * 2);

    int ebl = (NE + 255) / 256;
    int nbl = (NN + 255) / 256;

    // weight transpose+cvt (tiny, once)
    cvtT_k<<<(DD * DD + 255) / 256, 256, 0, stream>>>(W1, W1T, DD, DD);
    cvtT_k<<<(DD * DD + 255) / 256, 256, 0, stream>>>(W2, W2T, DD, DD);
    cvtT_k<<<(DD * DFF + 255) / 256, 256, 0, stream>>>(Wf1, Wf1T, DD, DFF);   // [512][128]
    cvtT_k<<<(DD * DFF + 255) / 256, 256, 0, stream>>>(Wf2, Wf2T, DFF, DD);   // [128][512]

    // CSR build (hierarchical scan)
    zero_int_k<<<nbl, 256, 0, stream>>>(cnt, NN);
    count_k<<<ebl, 256, 0, stream>>>(ei + NE, cnt);
    blksum_k<<<SCAN_NB, 256, 0, stream>>>(cnt, partials);
    scanpart_k<<<1, 256, 0, stream>>>(partials);
    scanapply_k<<<SCAN_NB, 256, 0, stream>>>(cnt, partials, row_start, cursor);
    scatter_k<<<ebl, 256, 0, stream>>>(ei, cursor, e_src, perm);

    int gbl = (NN + 127) / 128;
    int wbl = (NN + 3) / 4;
    int sbl = (NN * HH + 255) / 256;

    // ---- GAT layer 1 ----
    se_k<<<ebl, 256, 0, stream>>>(ew, We1, ae1, perm, s_e);
    gemm_mfma_k<<<gbl, 256, 0, stream>>>(nf, W1T, xh);
    ssd_k<<<sbl, 256, 0, stream>>>(xh, as1, ad1, s_src, s_dst);
    agg_k<<<wbl, 256, 0, stream>>>(row_start, e_src, s_src, s_dst, s_e, xh, h_out);
    ln_k<<<wbl, 256, 0, stream>>>(h_out, b1, g1, be1, nf, nf_cur);

    // ---- GAT layer 2 ----
    se_k<<<ebl, 256, 0, stream>>>(ew, We2, ae2, perm, s_e);
    gemm_mfma_k<<<gbl, 256, 0, stream>>>(nf_cur, W2T, xh);
    ssd_k<<<sbl, 256, 0, stream>>>(xh, as2, ad2, s_src, s_dst);
    agg_k<<<wbl, 256, 0, stream>>>(row_start, e_src, s_src, s_dst, s_e, xh, h_out);
    ln_k<<<wbl, 256, 0, stream>>>(h_out, b2, g2, be2, nf_cur, nf_cur);

    // ---- FFN ----
    ffn_mfma_k<<<(NN + 31) / 32, 256, 0, stream>>>(nf_cur, Wf1T, bf1, Wf2T, h_out);
    ln_k<<<wbl, 256, 0, stream>>>(h_out, bf2, g3, be3, nf_cur, out);
}

// Round 5
// 399.804 us; speedup vs baseline: 2.0092x; 1.1918x over previous
//
#include <hip/hip_runtime.h>
#include <hip/hip_bf16.h>

#define NN 50000
#define NE 800000
#define DD 128
#define HH 8
#define CC 16
#define DFF 512
#define ED 16
#define SCAN_NB ((NN + 255) / 256)   // 196

typedef __attribute__((ext_vector_type(8))) short bf16x8;
typedef __attribute__((ext_vector_type(4))) float f32x4;

union U8 { bf16x8 v; unsigned short s[8]; };

__device__ inline unsigned short f2bf(float f) {
    union { float f; unsigned u; } v; v.f = f;
    return (unsigned short)((v.u + 0x7fffu + ((v.u >> 16) & 1u)) >> 16);
}
__device__ inline float bf2f(unsigned s) {
    union { unsigned u; float f; } v; v.u = s << 16;
    return v.f;
}

// ---------------- utility ----------------
__global__ void zero_int_k(int* __restrict__ a, int n) {
    int i = blockIdx.x * 256 + threadIdx.x;
    if (i < n) a[i] = 0;
}

// transpose + cvt weights: in [K][Nc] f32 -> out [Nc][K] bf16
__global__ void cvtT_k(const float* __restrict__ in, unsigned short* __restrict__ outT,
                       int K, int Nc) {
    int idx = blockIdx.x * 256 + threadIdx.x;
    if (idx >= K * Nc) return;
    int n = idx / K, k = idx - n * K;
    outT[idx] = f2bf(in[(size_t)k * Nc + n]);
}

// ---------------- CSR build ----------------
__global__ void count_k(const int* __restrict__ dst, int* __restrict__ cnt) {
    int e = blockIdx.x * 256 + threadIdx.x;
    if (e < NE) atomicAdd(&cnt[dst[e]], 1);
}

__global__ void blksum_k(const int* __restrict__ cnt, int* __restrict__ partials) {
    int i = blockIdx.x * 256 + threadIdx.x;
    int v = (i < NN) ? cnt[i] : 0;
#pragma unroll
    for (int m = 1; m < 64; m <<= 1) v += __shfl_xor(v, m, 64);
    __shared__ int ws[4];
    if ((threadIdx.x & 63) == 0) ws[threadIdx.x >> 6] = v;
    __syncthreads();
    if (threadIdx.x == 0) partials[blockIdx.x] = ws[0] + ws[1] + ws[2] + ws[3];
}

__global__ void scanpart_k(int* __restrict__ partials) {
    __shared__ int buf[256];
    int t = threadIdx.x;
    int v = (t < SCAN_NB) ? partials[t] : 0;
    buf[t] = v;
    __syncthreads();
    for (int off = 1; off < 256; off <<= 1) {
        int u = (t >= off) ? buf[t - off] : 0;
        __syncthreads();
        buf[t] += u;
        __syncthreads();
    }
    if (t < SCAN_NB) partials[t] = buf[t] - v;  // exclusive
}

__global__ void scanapply_k(const int* __restrict__ cnt, const int* __restrict__ partials,
                            int* __restrict__ row_start, int* __restrict__ cursor) {
    __shared__ int buf[256];
    int t = threadIdx.x;
    int i = blockIdx.x * 256 + t;
    int v = (i < NN) ? cnt[i] : 0;
    buf[t] = v;
    __syncthreads();
    for (int off = 1; off < 256; off <<= 1) {
        int u = (t >= off) ? buf[t - off] : 0;
        __syncthreads();
        buf[t] += u;
        __syncthreads();
    }
    int excl = buf[t] - v + partials[blockIdx.x];
    if (i < NN) {
        row_start[i] = excl;
        cursor[i] = excl;
        if (i == NN - 1) row_start[NN] = excl + v;
    }
}

__global__ void scatter_k(const int* __restrict__ ei, int* __restrict__ cursor,
                          int* __restrict__ e_src, int* __restrict__ perm) {
    int e = blockIdx.x * 256 + threadIdx.x;
    if (e >= NE) return;
    int s = ei[e];
    int d = ei[NE + e];
    int pos = atomicAdd(&cursor[d], 1);
    e_src[pos] = s;
    perm[e] = pos;
}

// ---------------- edge scores ----------------
__global__ void se_k(const float* __restrict__ ew, const float* __restrict__ We,
                     const float* __restrict__ ae, const int* __restrict__ perm,
                     float* __restrict__ s_e) {
    __shared__ float Ae[ED * HH];
    int t = threadIdx.x;
    if (t < ED * HH) {
        int k = t >> 3, h = t & 7;
        float s = 0.f;
#pragma unroll
        for (int c = 0; c < CC; c++) s += We[k * DD + h * CC + c] * ae[h * CC + c];
        Ae[t] = s;
    }
    __syncthreads();
    int e = blockIdx.x * 256 + t;
    if (e >= NE) return;
    const float* ep = &ew[(size_t)e * ED];
    float4 v0 = *(const float4*)(ep);
    float4 v1 = *(const float4*)(ep + 4);
    float4 v2 = *(const float4*)(ep + 8);
    float4 v3 = *(const float4*)(ep + 12);
    float ev[16] = {v0.x, v0.y, v0.z, v0.w, v1.x, v1.y, v1.z, v1.w,
                    v2.x, v2.y, v2.z, v2.w, v3.x, v3.y, v3.z, v3.w};
    float o[8] = {0, 0, 0, 0, 0, 0, 0, 0};
#pragma unroll
    for (int k = 0; k < 16; k++) {
        float v = ev[k];
#pragma unroll
        for (int h = 0; h < 8; h++) o[h] += v * Ae[k * 8 + h];
    }
    int pp = perm[e];
    *(float4*)&s_e[(size_t)pp * 8]     = make_float4(o[0], o[1], o[2], o[3]);
    *(float4*)&s_e[(size_t)pp * 8 + 4] = make_float4(o[4], o[5], o[6], o[7]);
}

// ---------------- MFMA node GEMM: Y = X @ W ; also emits bf16 copy ----------------
__global__ __launch_bounds__(256) void gemm_mfma_k(const float* __restrict__ X,
                                                   const unsigned short* __restrict__ WT,
                                                   float* __restrict__ Y,
                                                   unsigned short* __restrict__ Ybf) {
    __shared__ char Xl[128 * 256];  // bf16 [row][128], XOR-swizzled
    int t = threadIdx.x;
    int nb0 = blockIdx.x * 128;
    for (int c = t; c < 2048; c += 256) {
        int row = c >> 4, cb = c & 15;
        int n = nb0 + row;
        U8 u;
        if (n < NN) {
            const float* xp = &X[(size_t)n * DD + cb * 8];
            float4 a = *(const float4*)xp;
            float4 b = *(const float4*)(xp + 4);
            u.s[0] = f2bf(a.x); u.s[1] = f2bf(a.y); u.s[2] = f2bf(a.z); u.s[3] = f2bf(a.w);
            u.s[4] = f2bf(b.x); u.s[5] = f2bf(b.y); u.s[6] = f2bf(b.z); u.s[7] = f2bf(b.w);
        } else {
#pragma unroll
            for (int q = 0; q < 8; q++) u.s[q] = 0;
        }
        int byte = (row * 256 + cb * 16) ^ ((row & 7) << 4);
        *(bf16x8*)&Xl[byte] = u.v;
    }
    __syncthreads();
    int w = t >> 6, l = t & 63;
    int lrow = l & 15, lq = l >> 4;
    int r0 = (w & 1) * 64, c0 = (w >> 1) * 64;
    f32x4 acc[4][4];
#pragma unroll
    for (int i = 0; i < 4; i++)
#pragma unroll
        for (int j = 0; j < 4; j++) acc[i][j] = (f32x4){0.f, 0.f, 0.f, 0.f};
#pragma unroll
    for (int ks = 0; ks < 4; ks++) {
        int k0 = ks * 32;
        bf16x8 af[4], bq[4];
#pragma unroll
        for (int i = 0; i < 4; i++) {
            int rr = r0 + i * 16 + lrow;
            int byte = (rr * 256 + k0 * 2 + lq * 16) ^ ((rr & 7) << 4);
            af[i] = *(const bf16x8*)&Xl[byte];
        }
#pragma unroll
        for (int j = 0; j < 4; j++) {
            int cc = c0 + j * 16 + lrow;
            bq[j] = *(const bf16x8*)&WT[(size_t)cc * DD + k0 + lq * 8];
        }
#pragma unroll
        for (int i = 0; i < 4; i++)
#pragma unroll
            for (int j = 0; j < 4; j++)
                acc[i][j] = __builtin_amdgcn_mfma_f32_16x16x32_bf16(af[i], bq[j], acc[i][j], 0, 0, 0);
    }
#pragma unroll
    for (int i = 0; i < 4; i++) {
#pragma unroll
        for (int j = 0; j < 4; j++) {
#pragma unroll
            for (int q = 0; q < 4; q++) {
                int n = nb0 + r0 + i * 16 + lq * 4 + q;
                if (n < NN) {
                    float v = acc[i][j][q];
                    size_t off = (size_t)n * DD + c0 + j * 16 + lrow;
                    Y[off] = v;
                    Ybf[off] = f2bf(v);
                }
            }
        }
    }
}

// ---------------- s_src/s_dst ----------------
__global__ void ssd_k(const float* __restrict__ xh, const float* __restrict__ a_src,
                      const float* __restrict__ a_dst, float* __restrict__ s_src,
                      float* __restrict__ s_dst) {
    __shared__ float as[128], ad[128];
    if (threadIdx.x < 128) {
        as[threadIdx.x] = a_src[threadIdx.x];
        ad[threadIdx.x] = a_dst[threadIdx.x];
    }
    __syncthreads();
    int idx = blockIdx.x * 256 + threadIdx.x;
    if (idx >= NN * HH) return;
    int n = idx >> 3, h = idx & 7;
    const float* x = &xh[(size_t)n * DD + h * CC];
    float s1 = 0.f, s2 = 0.f;
#pragma unroll
    for (int c = 0; c < CC; c++) {
        float v = x[c];
        s1 += v * as[h * CC + c];
        s2 += v * ad[h * CC + c];
    }
    s_src[idx] = s1;
    s_dst[idx] = s2;
}

// ---------------- aggregation: one wave per destination node, bf16 gather, unroll-2 ----------------
__global__ __launch_bounds__(256) void agg_k(const int* __restrict__ row_start,
                                             const int* __restrict__ e_src,
                                             const float* __restrict__ s_src,
                                             const float* __restrict__ s_dst,
                                             const float* __restrict__ s_e,
                                             const unsigned short* __restrict__ xh_bf,
                                             float* __restrict__ out) {
    int wid = (blockIdx.x * 256 + threadIdx.x) >> 6;
    if (wid >= NN) return;
    int lane = threadIdx.x & 63;
    int h = lane >> 3;
    float sdst = s_dst[wid * 8 + h];
    int beg = row_start[wid], end = row_start[wid + 1];
    float acc0 = 0.f, acc1 = 0.f, z = 0.f;
    int p = beg;
    for (; p + 2 <= end; p += 2) {
        int s0 = e_src[p];
        int s1 = e_src[p + 1];
        float a0 = s_src[s0 * 8 + h] + sdst + s_e[(size_t)p * 8 + h];
        float a1 = s_src[s1 * 8 + h] + sdst + s_e[(size_t)(p + 1) * 8 + h];
        unsigned u0 = *(const unsigned*)&xh_bf[(size_t)s0 * DD + lane * 2];
        unsigned u1 = *(const unsigned*)&xh_bf[(size_t)s1 * DD + lane * 2];
        a0 = (a0 > 0.f) ? a0 : 0.2f * a0;
        a1 = (a1 > 0.f) ? a1 : 0.2f * a1;
        float e0 = __expf(a0);
        float e1 = __expf(a1);
        z += e0 + e1;
        acc0 = fmaf(e0, bf2f(u0 & 0xffffu), acc0);
        acc1 = fmaf(e0, bf2f(u0 >> 16), acc1);
        acc0 = fmaf(e1, bf2f(u1 & 0xffffu), acc0);
        acc1 = fmaf(e1, bf2f(u1 >> 16), acc1);
    }
    if (p < end) {
        int s0 = e_src[p];
        float a0 = s_src[s0 * 8 + h] + sdst + s_e[(size_t)p * 8 + h];
        unsigned u0 = *(const unsigned*)&xh_bf[(size_t)s0 * DD + lane * 2];
        a0 = (a0 > 0.f) ? a0 : 0.2f * a0;
        float e0 = __expf(a0);
        z += e0;
        acc0 = fmaf(e0, bf2f(u0 & 0xffffu), acc0);
        acc1 = fmaf(e0, bf2f(u0 >> 16), acc1);
    }
    float inv = 1.f / (z + 1e-16f);
    *(float2*)&out[(size_t)wid * DD + lane * 2] = make_float2(acc0 * inv, acc1 * inv);
}

// ---------------- bias + LayerNorm(ddof=1) + leaky_relu + residual ----------------
__global__ __launch_bounds__(256) void ln_k(const float* __restrict__ hin,
                                            const float* __restrict__ bias,
                                            const float* __restrict__ g,
                                            const float* __restrict__ be,
                                            const float* __restrict__ res,
                                            float* __restrict__ out) {
    int wid = (blockIdx.x * 256 + threadIdx.x) >> 6;
    if (wid >= NN) return;
    int lane = threadIdx.x & 63;
    float2 x = *(const float2*)&hin[(size_t)wid * DD + lane * 2];
    float2 b = *(const float2*)&bias[lane * 2];
    x.x += b.x;
    x.y += b.y;
    float s = x.x + x.y;
    float q = x.x * x.x + x.y * x.y;
#pragma unroll
    for (int m = 1; m < 64; m <<= 1) {
        s += __shfl_xor(s, m, 64);
        q += __shfl_xor(q, m, 64);
    }
    float mu = s * (1.f / 128.f);
    float var = (q - 128.f * mu * mu) * (1.f / 127.f);
    float sd = sqrtf(fmaxf(var, 0.f));
    float inv = 1.f / (sd + 1e-6f);
    float2 gg = *(const float2*)&g[lane * 2];
    float2 bb = *(const float2*)&be[lane * 2];
    float y0 = gg.x * (x.x - mu) * inv + bb.x;
    float y1 = gg.y * (x.y - mu) * inv + bb.y;
    y0 = (y0 > 0.f) ? y0 : 0.01f * y0;
    y1 = (y1 > 0.f) ? y1 : 0.01f * y1;
    float2 r = *(const float2*)&res[(size_t)wid * DD + lane * 2];
    *(float2*)&out[(size_t)wid * DD + lane * 2] = make_float2(r.x + y0, r.y + y1);
}

// ---------------- fused MFMA FFN: 32 nodes/block ----------------
__global__ __launch_bounds__(256) void ffn_mfma_k(const float* __restrict__ X,
                                                  const unsigned short* __restrict__ Wf1T,
                                                  const float* __restrict__ bf1,
                                                  const unsigned short* __restrict__ Wf2T,
                                                  float* __restrict__ out) {
    __shared__ char Xl[32 * 256];    // bf16 [32][128] swizzled
    __shared__ char Hl[32 * 1024];   // bf16 [32][512] swizzled
    int t = threadIdx.x;
    int nb0 = blockIdx.x * 32;
    for (int c = t; c < 512; c += 256) {
        int row = c >> 4, cb = c & 15;
        int n = nb0 + row;
        U8 u;
        if (n < NN) {
            const float* xp = &X[(size_t)n * DD + cb * 8];
            float4 a = *(const float4*)xp;
            float4 b = *(const float4*)(xp + 4);
            u.s[0] = f2bf(a.x); u.s[1] = f2bf(a.y); u.s[2] = f2bf(a.z); u.s[3] = f2bf(a.w);
            u.s[4] = f2bf(b.x); u.s[5] = f2bf(b.y); u.s[6] = f2bf(b.z); u.s[7] = f2bf(b.w);
        } else {
#pragma unroll
            for (int q = 0; q < 8; q++) u.s[q] = 0;
        }
        int byte = (row * 256 + cb * 16) ^ ((row & 7) << 4);
        *(bf16x8*)&Xl[byte] = u.v;
    }
    __syncthreads();
    int w = t >> 6, l = t & 63;
    int lrow = l & 15, lq = l >> 4;
    // ---- phase A ----
    {
        int u0 = w * 128;
        f32x4 acc[2][8];
#pragma unroll
        for (int i = 0; i < 2; i++)
#pragma unroll
            for (int j = 0; j < 8; j++) acc[i][j] = (f32x4){0.f, 0.f, 0.f, 0.f};
#pragma unroll
        for (int ks = 0; ks < 4; ks++) {
            int k0 = ks * 32;
            bf16x8 af[2], bq[8];
#pragma unroll
            for (int i = 0; i < 2; i++) {
                int rr = i * 16 + lrow;
                int byte = (rr * 256 + k0 * 2 + lq * 16) ^ ((rr & 7) << 4);
                af[i] = *(const bf16x8*)&Xl[byte];
            }
#pragma unroll
            for (int j = 0; j < 8; j++) {
                int cc = u0 + j * 16 + lrow;
                bq[j] = *(const bf16x8*)&Wf1T[(size_t)cc * DD + k0 + lq * 8];
            }
#pragma unroll
            for (int i = 0; i < 2; i++)
#pragma unroll
                for (int j = 0; j < 8; j++)
                    acc[i][j] = __builtin_amdgcn_mfma_f32_16x16x32_bf16(af[i], bq[j], acc[i][j], 0, 0, 0);
        }
        float bias[8];
#pragma unroll
        for (int j = 0; j < 8; j++) bias[j] = bf1[u0 + j * 16 + lrow];
#pragma unroll
        for (int i = 0; i < 2; i++) {
#pragma unroll
            for (int j = 0; j < 8; j++) {
#pragma unroll
                for (int q = 0; q < 4; q++) {
                    float v = acc[i][j][q] + bias[j];
                    v = fmaxf(v, 0.f);
                    int row = i * 16 + lq * 4 + q;
                    int col = u0 + j * 16 + lrow;
                    int byte = (row * 1024 + col * 2) ^ ((row & 7) << 4);
                    *(unsigned short*)&Hl[byte] = f2bf(v);
                }
            }
        }
    }
    __syncthreads();
    // ---- phase B ----
    {
        int c0 = w * 32;
        f32x4 acc2[2][2];
#pragma unroll
        for (int i = 0; i < 2; i++)
#pragma unroll
            for (int j = 0; j < 2; j++) acc2[i][j] = (f32x4){0.f, 0.f, 0.f, 0.f};
        for (int ks = 0; ks < 16; ks++) {
            int k0 = ks * 32;
            bf16x8 af[2], bq[2];
#pragma unroll
            for (int i = 0; i < 2; i++) {
                int rr = i * 16 + lrow;
                int byte = (rr * 1024 + k0 * 2 + lq * 16) ^ ((rr & 7) << 4);
                af[i] = *(const bf16x8*)&Hl[byte];
            }
#pragma unroll
            for (int j = 0; j < 2; j++) {
                int cc = c0 + j * 16 + lrow;
                bq[j] = *(const bf16x8*)&Wf2T[(size_t)cc * DFF + k0 + lq * 8];
            }
#pragma unroll
            for (int i = 0; i < 2; i++)
#pragma unroll
                for (int j = 0; j < 2; j++)
                    acc2[i][j] = __builtin_amdgcn_mfma_f32_16x16x32_bf16(af[i], bq[j], acc2[i][j], 0, 0, 0);
        }
#pragma unroll
        for (int i = 0; i < 2; i++) {
#pragma unroll
            for (int j = 0; j < 2; j++) {
#pragma unroll
                for (int q = 0; q < 4; q++) {
                    int n = nb0 + i * 16 + lq * 4 + q;
                    if (n < NN) out[(size_t)n * DD + c0 + j * 16 + lrow] = acc2[i][j][q];
                }
            }
        }
    }
}

extern "C" void kernel_launch(void* const* d_in, const int* in_sizes, int n_in,
                              void* d_out, int out_size, void* d_ws, size_t ws_size,
                              hipStream_t stream) {
    const float* nf  = (const float*)d_in[0];
    const int*   ei  = (const int*)d_in[1];
    const float* ew  = (const float*)d_in[2];
    const float* W1  = (const float*)d_in[3];
    const float* as1 = (const float*)d_in[4];
    const float* ad1 = (const float*)d_in[5];
    const float* We1 = (const float*)d_in[6];
    const float* ae1 = (const float*)d_in[7];
    const float* b1  = (const float*)d_in[8];
    const float* g1  = (const float*)d_in[9];
    const float* be1 = (const float*)d_in[10];
    const float* W2  = (const float*)d_in[11];
    const float* as2 = (const float*)d_in[12];
    const float* ad2 = (const float*)d_in[13];
    const float* We2 = (const float*)d_in[14];
    const float* ae2 = (const float*)d_in[15];
    const float* b2  = (const float*)d_in[16];
    const float* g2  = (const float*)d_in[17];
    const float* be2 = (const float*)d_in[18];
    const float* Wf1 = (const float*)d_in[19];
    const float* bf1 = (const float*)d_in[20];
    const float* Wf2 = (const float*)d_in[21];
    const float* bf2 = (const float*)d_in[22];
    const float* g3  = (const float*)d_in[23];
    const float* be3 = (const float*)d_in[24];
    float* out = (float*)d_out;

    char* p = (char*)d_ws;
    auto alloc = [&](size_t bytes) {
        char* r = p;
        p += (bytes + 255) & ~(size_t)255;
        return r;
    };
    float* nf_cur = (float*)alloc((size_t)NN * DD * 4);
    float* xh     = (float*)alloc((size_t)NN * DD * 4);
    float* h_out  = (float*)alloc((size_t)NN * DD * 4);
    unsigned short* xh_bf = (unsigned short*)alloc((size_t)NN * DD * 2);
    float* s_e    = (float*)alloc((size_t)NE * HH * 4);
    float* s_src  = (float*)alloc((size_t)NN * HH * 4);
    float* s_dst  = (float*)alloc((size_t)NN * HH * 4);
    int* row_start = (int*)alloc((size_t)(NN + 1) * 4);
    int* cnt       = (int*)alloc((size_t)NN * 4);
    int* cursor    = (int*)alloc((size_t)NN * 4);
    int* partials  = (int*)alloc((size_t)SCAN_NB * 4);
    int* e_src     = (int*)alloc((size_t)NE * 4);
    int* perm      = (int*)alloc((size_t)NE * 4);
    unsigned short* W1T  = (unsigned short*)alloc((size_t)DD * DD * 2);
    unsigned short* W2T  = (unsigned short*)alloc((size_t)DD * DD * 2);
    unsigned short* Wf1T = (unsigned short*)alloc((size_t)DFF * DD * 2);
    unsigned short* Wf2T = (unsigned short*)alloc((size_t)DD * DFF * 2);

    int ebl = (NE + 255) / 256;
    int nbl = (NN + 255) / 256;

    // weight transpose+cvt (tiny, once)
    cvtT_k<<<(DD * DD + 255) / 256, 256, 0, stream>>>(W1, W1T, DD, DD);
    cvtT_k<<<(DD * DD + 255) / 256, 256, 0, stream>>>(W2, W2T, DD, DD);
    cvtT_k<<<(DD * DFF + 255) / 256, 256, 0, stream>>>(Wf1, Wf1T, DD, DFF);   // [512][128]
    cvtT_k<<<(DD * DFF + 255) / 256, 256, 0, stream>>>(Wf2, Wf2T, DFF, DD);   // [128][512]

    // CSR build (hierarchical scan)
    zero_int_k<<<nbl, 256, 0, stream>>>(cnt, NN);
    count_k<<<ebl, 256, 0, stream>>>(ei + NE, cnt);
    blksum_k<<<SCAN_NB, 256, 0, stream>>>(cnt, partials);
    scanpart_k<<<1, 256, 0, stream>>>(partials);
    scanapply_k<<<SCAN_NB, 256, 0, stream>>>(cnt, partials, row_start, cursor);
    scatter_k<<<ebl, 256, 0, stream>>>(ei, cursor, e_src, perm);

    int gbl = (NN + 127) / 128;
    int wbl = (NN + 3) / 4;
    int sbl = (NN * HH + 255) / 256;

    // ---- GAT layer 1 ----
    se_k<<<ebl, 256, 0, stream>>>(ew, We1, ae1, perm, s_e);
    gemm_mfma_k<<<gbl, 256, 0, stream>>>(nf, W1T, xh, xh_bf);
    ssd_k<<<sbl, 256, 0, stream>>>(xh, as1, ad1, s_src, s_dst);
    agg_k<<<wbl, 256, 0, stream>>>(row_start, e_src, s_src, s_dst, s_e, xh_bf, h_out);
    ln_k<<<wbl, 256, 0, stream>>>(h_out, b1, g1, be1, nf, nf_cur);

    // ---- GAT layer 2 ----
    se_k<<<ebl, 256, 0, stream>>>(ew, We2, ae2, perm, s_e);
    gemm_mfma_k<<<gbl, 256, 0, stream>>>(nf_cur, W2T, xh, xh_bf);
    ssd_k<<<sbl, 256, 0, stream>>>(xh, as2, ad2, s_src, s_dst);
    agg_k<<<wbl, 256, 0, stream>>>(row_start, e_src, s_src, s_dst, s_e, xh_bf, h_out);
    ln_k<<<wbl, 256, 0, stream>>>(h_out, b2, g2, be2, nf_cur, nf_cur);

    // ---- FFN ----
    ffn_mfma_k<<<(NN + 31) / 32, 256, 0, stream>>>(nf_cur, Wf1T, bf1, Wf2T, h_out);
    ln_k<<<wbl, 256, 0, stream>>>(h_out, bf2, g3, be3, nf_cur, out);
}